// Round 8
// baseline (1669.542 us; speedup 1.0000x reference)
//
#include <hip/hip_runtime.h>
#include <math.h>

#define N_NODES   100000
#define D_FEAT    128
#define N_EDGES   3200000
#define L_FILTERS 10

#define NRB       ((N_NODES + 3) / 4)                  // row-blocks per feature half: 25000

#define RPB_LOG   7
#define RPB       128
#define NBUCKETS  ((N_NODES + RPB - 1) >> RPB_LOG)     // 782
#define CHUNK     8192
#define NA_BLOCKS ((N_EDGES + CHUNK - 1) / CHUNK)      // 391

typedef unsigned char  u8;
typedef unsigned int   u32;
typedef unsigned short u16;
typedef unsigned long long u64;
typedef float f32x2 __attribute__((ext_vector_type(2)));

static __device__ __forceinline__ u16 f2bf(float f) {
    u32 u = __float_as_uint(f);
    u32 r = (u + 0x7FFFu + ((u >> 16) & 1u)) >> 16;   // RNE
    return (u16)r;
}
static __device__ __forceinline__ float bf2f(u32 b) {
    return __uint_as_float(b << 16);
}
static __device__ __forceinline__ float fp8_to_f32(u32 byte) {
    f32x2 f = __builtin_amdgcn_cvt_pk_f32_fp8(byte, false);
    return f[0];
}

// ---------------- init: Xf8 = fp8(X)  (doubles as Zhat_10 = X) ----------------
__global__ void gpr_init(const float* __restrict__ X, u8* __restrict__ Xf8, int n4) {
    int i = blockIdx.x * blockDim.x + threadIdx.x;
    if (i >= n4) return;
    float4 v = ((const float4*)X)[i];
    u32 p01 = __builtin_amdgcn_cvt_pk_fp8_f32(v.x, v.y, 0, false) & 0xFFFFu;
    u32 p23 = __builtin_amdgcn_cvt_pk_fp8_f32(v.z, v.w, 0, false) & 0xFFFFu;
    __builtin_nontemporal_store(p01 | (p23 << 16), (u32*)Xf8 + i);
}

// ---------------- bucket histogram (LDS-private, 1 global atomic per bucket/block) ----
__global__ __launch_bounds__(256) void gpr_bucket_hist(const int* __restrict__ rows,
                                                       int* __restrict__ bcount) {
    __shared__ int hist[NBUCKETS];
    int t = threadIdx.x;
    for (int i = t; i < NBUCKETS; i += 256) hist[i] = 0;
    __syncthreads();
    int stride = gridDim.x * 256;
    for (int e = blockIdx.x * 256 + t; e < N_EDGES; e += stride)
        atomicAdd(&hist[rows[e] >> RPB_LOG], 1);
    __syncthreads();
    for (int i = t; i < NBUCKETS; i += 256)
        if (hist[i]) atomicAdd(&bcount[i], hist[i]);
}

// ---------------- scan 782 bucket counts (single block) ----------------
__global__ __launch_bounds__(1024) void gpr_bucket_scan(const int* __restrict__ bcount,
                                                        int* __restrict__ bucket_base,
                                                        int* __restrict__ bucket_cursor,
                                                        int* __restrict__ row_ptr) {
    __shared__ int buf[1024];
    int t = threadIdx.x;
    int v = (t < NBUCKETS) ? bcount[t] : 0;
    buf[t] = v; __syncthreads();
    for (int off = 1; off < 1024; off <<= 1) {
        int x = (t >= off) ? buf[t - off] : 0;
        __syncthreads();
        buf[t] += x;
        __syncthreads();
    }
    if (t < NBUCKETS) {
        int ex = buf[t] - v;
        bucket_base[t] = ex;
        bucket_cursor[t] = ex;
    }
    if (t == 0) {
        bucket_base[NBUCKETS] = N_EDGES;
        row_ptr[N_NODES] = N_EDGES;
    }
}

// ---------------- phase A: coarse bin into buckets, coalesced writes ----------------
// pack: val15[34:49) | row17[17:34) | col17[0:17)
__global__ __launch_bounds__(256) void gpr_binA(const int* __restrict__ rows,
                                                const int* __restrict__ cols,
                                                const float* __restrict__ vals,
                                                int* __restrict__ bucket_cursor,
                                                u64* __restrict__ packedA) {
    __shared__ u64 stage[CHUNK];
    __shared__ int hist[NBUCKETS];
    __shared__ int lbase[NBUCKETS];
    __shared__ int lcur[NBUCKETS];
    __shared__ int goff[NBUCKETS];
    __shared__ int psum[256];
    int t = threadIdx.x;
    long long base = (long long)blockIdx.x * CHUNK;
    for (int i = t; i < NBUCKETS; i += 256) hist[i] = 0;
    __syncthreads();
    for (int j = 0; j < CHUNK / 256; ++j) {
        long long e = base + j * 256 + t;
        if (e < N_EDGES) atomicAdd(&hist[rows[e] >> RPB_LOG], 1);
    }
    __syncthreads();
    int s = 0, b0 = t * 4;
    #pragma unroll
    for (int j = 0; j < 4; ++j) { int b = b0 + j; if (b < NBUCKETS) s += hist[b]; }
    psum[t] = s; __syncthreads();
    for (int off = 1; off < 256; off <<= 1) {
        int x = (t >= off) ? psum[t - off] : 0;
        __syncthreads();
        psum[t] += x;
        __syncthreads();
    }
    int run = psum[t] - s;
    #pragma unroll
    for (int j = 0; j < 4; ++j) {
        int b = b0 + j;
        if (b < NBUCKETS) { lbase[b] = run; run += hist[b]; }
    }
    __syncthreads();
    for (int i = t; i < NBUCKETS; i += 256) {
        lcur[i] = lbase[i];
        int g = (hist[i]) ? atomicAdd(&bucket_cursor[i], hist[i]) : 0;
        goff[i] = g - lbase[i];
    }
    __syncthreads();
    for (int j = 0; j < CHUNK / 256; ++j) {
        long long e = base + j * 256 + t;
        if (e < N_EDGES) {
            int r = rows[e];
            u32 vb = (u32)f2bf(vals[e]);
            u64 p = ((u64)vb << 34) | ((u64)(u32)r << 17) | (u64)(u32)cols[e];
            int pos = atomicAdd(&lcur[r >> RPB_LOG], 1);
            stage[pos] = p;
        }
    }
    __syncthreads();
    long long rem = (long long)N_EDGES - base;
    int total = (rem < CHUNK) ? (int)rem : CHUNK;
    for (int idx = t; idx < total; idx += 256) {
        u64 p = stage[idx];
        int b = (int)((p >> 17) & 0x1FFFFu) >> RPB_LOG;
        packedA[goff[b] + idx] = p;
    }
}

// ---------------- phase B: per-bucket row histogram + scan + row_ptr + fine scatter ----
__global__ __launch_bounds__(256) void gpr_binB(const int* __restrict__ bucket_base,
                                                const u64* __restrict__ packedA,
                                                int* __restrict__ row_ptr,
                                                u32* __restrict__ edges) {
    __shared__ int cnt[RPB];
    __shared__ int sbuf[RPB];
    __shared__ int cur[RPB];
    int b = blockIdx.x;
    int t = threadIdx.x;
    int r0 = b << RPB_LOG;
    int r1 = r0 + RPB; if (r1 > N_NODES) r1 = N_NODES;
    int lo = bucket_base[b], hi = bucket_base[b + 1];
    if (t < RPB) cnt[t] = 0;
    __syncthreads();
    for (int e = lo + t; e < hi; e += 256) {
        int r = (int)((packedA[e] >> 17) & 0x1FFFFu);
        atomicAdd(&cnt[r - r0], 1);
    }
    __syncthreads();
    if (t < RPB) sbuf[t] = cnt[t];
    __syncthreads();
    for (int off = 1; off < RPB; off <<= 1) {
        int x = (t < RPB && t >= off) ? sbuf[t - off] : 0;
        __syncthreads();
        if (t < RPB) sbuf[t] += x;
        __syncthreads();
    }
    if (t < RPB) {
        int ex = sbuf[t] - cnt[t];
        cur[t] = ex;
        if (r0 + t < r1) row_ptr[r0 + t] = lo + ex;
    }
    __syncthreads();
    for (int e = lo + t; e < hi; e += 256) {
        u64 p = packedA[e];
        int r = (int)((p >> 17) & 0x1FFFFu);
        int pos = lo + atomicAdd(&cur[r - r0], 1);
        edges[pos] = (u32)(((p >> 34) << 17) | (p & 0x1FFFFu));
    }
}

// ---------------- Horner SpMM, feature-half split ----------------
// Zhat_l = X + (w[l+1]/w[l]) * A * Zhat_{l+1}   (RD: 0=fp8, 1=bf16; WR: 0=fp8, 1=bf16, 2=f32)
// final:  out = w0*X + w1 * A * Zhat_1
// grid = 2*NRB: blocks [0,NRB) do feats 0-63, [NRB,2*NRB) do feats 64-127.
// One wave = one row-half; lane owns 1 feature.
template<int RD, int WR>
__global__ __launch_bounds__(256) void gpr_spmm(
    const int* __restrict__ row_ptr, const u32* __restrict__ edges,
    const void* __restrict__ Zold, const u8* __restrict__ Xf8,
    const float* __restrict__ Xf, const float* __restrict__ w, int l,
    void* __restrict__ Znew, float* __restrict__ out) {
    int bid = blockIdx.x;
    int half = (bid >= NRB) ? 1 : 0;
    int rb = bid - (half ? NRB : 0);
    int row = rb * 4 + (threadIdx.x >> 6);
    row = __builtin_amdgcn_readfirstlane(row);
    if (row >= N_NODES) return;
    int lane = threadIdx.x & 63;
    int fo = half * 64 + lane;                   // feature index [0,128)
    int start = row_ptr[row];
    int end   = row_ptr[row + 1];
    const u8*  Hf8 = (const u8*)Zold;
    const u16* Hbf = (const u16*)Zold;

    float acc = 0.0f;
    int i = start;
    int end4 = start + ((end - start) & ~3);
    for (; i < end4; i += 4) {
        u32 e0 = __builtin_nontemporal_load(&edges[i + 0]);
        u32 e1 = __builtin_nontemporal_load(&edges[i + 1]);
        u32 e2 = __builtin_nontemporal_load(&edges[i + 2]);
        u32 e3 = __builtin_nontemporal_load(&edges[i + 3]);
        float v0 = bf2f(e0 >> 17);
        float v1 = bf2f(e1 >> 17);
        float v2 = bf2f(e2 >> 17);
        float v3 = bf2f(e3 >> 17);
        float h0, h1, h2, h3;
        if (RD == 0) {
            h0 = fp8_to_f32(Hf8[(size_t)(e0 & 0x1FFFFu) * 128 + fo]);
            h1 = fp8_to_f32(Hf8[(size_t)(e1 & 0x1FFFFu) * 128 + fo]);
            h2 = fp8_to_f32(Hf8[(size_t)(e2 & 0x1FFFFu) * 128 + fo]);
            h3 = fp8_to_f32(Hf8[(size_t)(e3 & 0x1FFFFu) * 128 + fo]);
        } else {
            h0 = bf2f(Hbf[(size_t)(e0 & 0x1FFFFu) * 128 + fo]);
            h1 = bf2f(Hbf[(size_t)(e1 & 0x1FFFFu) * 128 + fo]);
            h2 = bf2f(Hbf[(size_t)(e2 & 0x1FFFFu) * 128 + fo]);
            h3 = bf2f(Hbf[(size_t)(e3 & 0x1FFFFu) * 128 + fo]);
        }
        acc = fmaf(v0, h0, acc);
        acc = fmaf(v1, h1, acc);
        acc = fmaf(v2, h2, acc);
        acc = fmaf(v3, h3, acc);
    }
    for (; i < end; ++i) {
        u32 e0 = __builtin_nontemporal_load(&edges[i]);
        float v0 = bf2f(e0 >> 17);
        float h0 = (RD == 0) ? fp8_to_f32(Hf8[(size_t)(e0 & 0x1FFFFu) * 128 + fo])
                             : bf2f(Hbf[(size_t)(e0 & 0x1FFFFu) * 128 + fo]);
        acc = fmaf(v0, h0, acc);
    }
    if (!isfinite(acc)) acc = 0.0f;

    size_t o = (size_t)row * 128 + fo;
    if (WR == 2) {
        float xv = Xf[o];
        float res = fmaf(w[1], acc, w[0] * xv);
        __builtin_nontemporal_store(res, out + o);
    } else {
        float xadd = fp8_to_f32(Xf8[o]);
        float cc = w[l + 1] / w[l];
        float z = fmaf(cc, acc, xadd);
        if (WR == 0) {
            u32 p = __builtin_amdgcn_cvt_pk_fp8_f32(z, z, 0, false);
            __builtin_nontemporal_store((u8)p, (u8*)Znew + o);
        } else {
            __builtin_nontemporal_store(f2bf(z), (u16*)Znew + o);
        }
    }
}

extern "C" void kernel_launch(void* const* d_in, const int* in_sizes, int n_in,
                              void* d_out, int out_size, void* d_ws, size_t ws_size,
                              hipStream_t stream) {
    const int*   erow  = (const int*)d_in[0];
    const int*   ecol  = (const int*)d_in[1];
    const float* evals = (const float*)d_in[2];
    const float* X     = (const float*)d_in[3];
    const float* w     = (const float*)d_in[4];
    float* out = (float*)d_out;

    const size_t n = (size_t)N_NODES * D_FEAT;  // 12.8M elements

    // workspace layout (~78 MB)
    char* base = (char*)d_ws;
    u8*  Xf8     = (u8*)base;                   // fp8, n bytes (also Zhat_10)
    u8*  Za      = (u8*)(base + n);             // fp8, n bytes
    u8*  Zb      = (u8*)(base + 2 * n);         // fp8, n bytes
    u16* Z1bf    = (u16*)(base + 3 * n);        // bf16, 2n bytes (aliases packedA)
    u64* packedA = (u64*)(base + 3 * n);        // 3.2M u64 = 25.6 MB, dead before hop k=1
    int* row_ptr = (int*)(base + 5 * n);        // 100001 (padded 100352)
    int* bucket_base   = row_ptr + 100352;
    int* bucket_cursor = bucket_base + 1024;
    int* bcount        = bucket_cursor + 1024;
    u32* edges   = (u32*)(bcount + 1024);       // 3.2M u32 = 12.8 MB

    dim3 b256(256);

    // CSR build
    hipMemsetAsync(bcount, 0, NBUCKETS * sizeof(int), stream);
    gpr_bucket_hist<<<dim3(512), b256, 0, stream>>>(erow, bcount);
    gpr_bucket_scan<<<dim3(1), dim3(1024), 0, stream>>>(bcount, bucket_base, bucket_cursor, row_ptr);
    gpr_binA<<<dim3(NA_BLOCKS), b256, 0, stream>>>(erow, ecol, evals, bucket_cursor, packedA);
    gpr_binB<<<dim3(NBUCKETS), b256, 0, stream>>>(bucket_base, packedA, row_ptr, edges);

    // Xf8 = fp8(X) = Zhat_10
    gpr_init<<<dim3((unsigned)((n / 4 + 255) / 256)), b256, 0, stream>>>(X, Xf8, (int)(n / 4));

    dim3 spmm_grid(2 * NRB);
    // hops k = 9..2: fp8 -> fp8   (Xf8 -> Za -> Zb -> Za ...)
    const void* Zold = Xf8;
    u8* bufs[2] = {Za, Zb};
    int tog = 0;
    for (int k = L_FILTERS - 1; k >= 2; --k) {
        u8* Znew = bufs[tog]; tog ^= 1;
        gpr_spmm<0, 0><<<spmm_grid, b256, 0, stream>>>(row_ptr, edges, Zold, Xf8, X, w, k, Znew, nullptr);
        Zold = Znew;
    }
    // hop k = 1: fp8 -> bf16 (protect the final A-application's input precision)
    gpr_spmm<0, 1><<<spmm_grid, b256, 0, stream>>>(row_ptr, edges, Zold, Xf8, X, w, 1, Z1bf, nullptr);
    // hop k = 0 (final): bf16 -> fp32 out = w0*X + w1*acc
    gpr_spmm<1, 2><<<spmm_grid, b256, 0, stream>>>(row_ptr, edges, Z1bf, Xf8, X, w, 0, nullptr, out);
}